// Round 4
// baseline (666.500 us; speedup 1.0000x reference)
//
#include <hip/hip_runtime.h>
#include <hip/hip_bf16.h>
#include <math.h>

#define N_NODES 65536
#define NDIR 9
#define NEDGE 589824
#define NBINS (N_NODES*16)          // bin = dst*16 + sel

typedef __attribute__((ext_vector_type(8))) short short8;
typedef __attribute__((ext_vector_type(4))) float f32x4;

__device__ inline float bf2f(unsigned short u){ return __uint_as_float(((unsigned int)u)<<16); }
__device__ inline unsigned short f2bf(float f){
  unsigned int x = __float_as_uint(f);
  x += 0x7fff + ((x>>16)&1);           // round-to-nearest-even
  return (unsigned short)(x>>16);
}
__device__ inline float elu1(float x){ return x>0.f ? x : expm1f(x); }

// ---- prep: fold BN scale into W, transpose to [n][k] bf16 ----
// Wt1 rows 0..1151 = conv1 dirs, rows 1152..1279 = W3*s3 (shortcut). Wt2 = conv2 dirs.
__global__ void prep_w(const float* __restrict__ W1, const float* __restrict__ W2,
                       const float* __restrict__ W3,
                       const float* __restrict__ g1, const float* __restrict__ rv1,
                       const float* __restrict__ g2, const float* __restrict__ rv2,
                       const float* __restrict__ g3, const float* __restrict__ rv3,
                       unsigned short* __restrict__ Wt1, unsigned short* __restrict__ Wt2){
  int idx = blockIdx.x*256 + threadIdx.x;
  const float eps = 1e-5f;
  if (idx < 1280*128) {
    int n = idx >> 7, k = idx & 127;
    float v;
    if (n < 1152) { int d = n >> 7, c = n & 127;
      float s = g1[c]*rsqrtf(rv1[c]+eps); v = W1[(d*128 + k)*128 + c] * s; }
    else { int c = n - 1152;
      float s = g3[c]*rsqrtf(rv3[c]+eps); v = W3[k*128 + c] * s; }
    Wt1[idx] = f2bf(v);
  } else {
    int j = idx - 1280*128;
    int n = j >> 7, k = j & 127;
    int d = n >> 7, c = n & 127;
    float s = g2[c]*rsqrtf(rv2[c]+eps);
    Wt2[j] = f2bf(W2[(d*128 + k)*128 + c] * s);
  }
}

__global__ void prep_bias(const float* b1,const float* g1,const float* be1,const float* rm1,const float* rv1,
                          const float* b2,const float* g2,const float* be2,const float* rm2,const float* rv2,
                          const float* b3,const float* g3,const float* be3,const float* rm3,const float* rv3,
                          float* bias1, float* bias2, float* bias3, float* s3v){
  int c = threadIdx.x;
  const float eps = 1e-5f;
  float s1 = g1[c]*rsqrtf(rv1[c]+eps);
  bias1[c] = (b1[c]-rm1[c])*s1 + be1[c];
  float s2 = g2[c]*rsqrtf(rv2[c]+eps);
  bias2[c] = (b2[c]-rm2[c])*s2 + be2[c];
  float s3 = g3[c]*rsqrtf(rv3[c]+eps);
  bias3[c] = (b3[c]-rm3[c])*s3 + be3[c];   // sc bias: (b3-rm3)*s3+be3; s3 folded into Wt3
  s3v[c] = s3;
}

// ---- cast x to bf16 once ----
__global__ void xcast_k(const float* __restrict__ x, unsigned short* __restrict__ xb){
  int i = (blockIdx.x*256 + threadIdx.x)*8;
  f32x4 f0 = *(const f32x4*)(x + i);
  f32x4 f1 = *(const f32x4*)(x + i + 4);
  short8 t;
  #pragma unroll
  for (int j = 0; j < 4; j++){ t[j] = (short)f2bf(f0[j]); t[4+j] = (short)f2bf(f1[j]); }
  *(short8*)(xb + i) = t;
}

// ---- CSR build over (dst,sel) bins ----
__global__ void hist_k(const int* __restrict__ dst, const int* __restrict__ sel,
                       int* __restrict__ hist){
  int e = blockIdx.x*256 + threadIdx.x;
  atomicAdd(&hist[dst[e]*16 + sel[e]], 1);
}

// exclusive scan of 1024 ints per block; block total -> bsum[blockIdx]
__global__ void scan1_k(const int* __restrict__ in, int* __restrict__ out, int* __restrict__ bsum){
  __shared__ int wsum[4];
  int t = threadIdx.x;
  int base = blockIdx.x*1024 + t*4;
  int4 v = *(const int4*)(in + base);
  int s = v.x + v.y + v.z + v.w;
  int lane = t & 63, w = t >> 6;
  int inc = s;
  #pragma unroll
  for (int o = 1; o < 64; o <<= 1){ int n = __shfl_up(inc, o); if (lane >= o) inc += n; }
  if (lane == 63) wsum[w] = inc;
  __syncthreads();
  int acc = 0;
  for (int i = 0; i < w; i++) acc += wsum[i];
  int ex = acc + inc - s;
  out[base] = ex; out[base+1] = ex + v.x; out[base+2] = ex + v.x + v.y; out[base+3] = ex + v.x + v.y + v.z;
  if (t == 255) bsum[blockIdx.x] = acc + inc;
}

__global__ void scan3_k(int* __restrict__ rs, const int* __restrict__ bsumx, int* __restrict__ cursor){
  int i = blockIdx.x*256 + threadIdx.x;
  int v = rs[i] + bsumx[i >> 10];
  rs[i] = v; cursor[i] = v;
}

__global__ void scatter_k(const int* __restrict__ src, const int* __restrict__ dst,
                          const int* __restrict__ sel,
                          int* __restrict__ cursor, int* __restrict__ sorted){
  int e = blockIdx.x*256 + threadIdx.x;
  int bin = dst[e]*16 + sel[e];
  int pos = atomicAdd(&cursor[bin], 1);
  sorted[pos] = src[e];                 // after scatter, cursor[bin] == end
}

// ---- fused layer: per 64-node block, for each dir: gather-sum rows -> LDS tile,
// MFMA tile @ W_d, accumulate in regs. L2 adds x-gather @ W3 shortcut at d==0. ----
__device__ inline void gather_dir(const unsigned short* __restrict__ act,
                                  const int* __restrict__ rs, const int* __restrict__ ce,
                                  const int* __restrict__ sorted,
                                  unsigned short* agg, int m0, int d, int g, int r8){
  #pragma unroll
  for (int it = 0; it < 2; it++){
    int nl = it*32 + g;
    int bin = (m0 + nl)*16 + d;
    int s = rs[bin], e = ce[bin];
    float a0[8], a1[8];
    #pragma unroll
    for (int j = 0; j < 8; j++){ a0[j] = 0.f; a1[j] = 0.f; }
    for (int i = s; i < e; i++){
      int srcn = sorted[i];
      const unsigned short* row = act + (size_t)srcn*128 + r8*8;
      short8 v0 = *(const short8*)row;
      short8 v1 = *(const short8*)(row + 64);
      #pragma unroll
      for (int j = 0; j < 8; j++){ a0[j] += bf2f((unsigned short)v0[j]); a1[j] += bf2f((unsigned short)v1[j]); }
    }
    short8 o0, o1;
    #pragma unroll
    for (int j = 0; j < 8; j++){ o0[j] = (short)f2bf(a0[j]); o1[j] = (short)f2bf(a1[j]); }
    *(short8*)&agg[nl*136 + r8*8] = o0;
    *(short8*)&agg[nl*136 + 64 + r8*8] = o1;
  }
}

__device__ inline void mfma_tile(f32x4* acc, const unsigned short* agg,
                                 const unsigned short* __restrict__ W,
                                 int w, int q, int r){
  #pragma unroll
  for (int kk = 0; kk < 4; kk++){
    short8 av = *(const short8*)&agg[(w*16 + r)*136 + kk*32 + q*8];
    #pragma unroll
    for (int ns = 0; ns < 8; ns++){
      short8 bv = *(const short8*)(W + (size_t)(ns*16 + r)*128 + kk*32 + q*8);
      acc[ns] = __builtin_amdgcn_mfma_f32_16x16x32_bf16(av, bv, acc[ns], 0, 0, 0);
    }
  }
}

template<int IS_L2>
__global__ __launch_bounds__(256, 4 - IS_L2) void layer_k(
    const unsigned short* __restrict__ H,     // layer input activations [N][128] bf16
    const unsigned short* __restrict__ X,     // xb (shortcut input, L2 only)
    const unsigned short* __restrict__ Wf,    // [1152][128] folded dir weights
    const unsigned short* __restrict__ W3f,   // [128][128] folded shortcut weights (L2)
    const int* __restrict__ rs, const int* __restrict__ ce, const int* __restrict__ sorted,
    const float* __restrict__ biasA, const float* __restrict__ bias3,
    const float* __restrict__ s3v,
    unsigned short* __restrict__ outB, float* __restrict__ outF){
  __shared__ __align__(16) unsigned short agg[2*64*136];   // tile + (L2) shortcut tile
  unsigned short* agg2 = agg + 64*136;
  const int tid = threadIdx.x;
  const int w = tid >> 6, lane = tid & 63;
  const int q = lane >> 4, r = lane & 15;
  const int g = tid >> 3, r8 = tid & 7;
  const int m0 = blockIdx.x * 64;

  f32x4 acc[8];
  #pragma unroll
  for (int ns = 0; ns < 8; ns++) acc[ns] = (f32x4){0.f,0.f,0.f,0.f};
  f32x4 sca[8];
  if constexpr (IS_L2){
    #pragma unroll
    for (int ns = 0; ns < 8; ns++) sca[ns] = (f32x4){0.f,0.f,0.f,0.f};
  }

  #pragma unroll 1
  for (int dd = 0; dd < 9; dd++){
    int d = dd + 1 == 9 ? 0 : dd + 1;   // process 1..8 then 0 (keeps sca live-range short)
    if constexpr (IS_L2){
      if (d == 0){
        // fused dual gather: h-rows and x-rows over the same sel==0 edges
        #pragma unroll
        for (int it = 0; it < 2; it++){
          int nl = it*32 + g;
          int bin = (m0 + nl)*16;
          int s = rs[bin], e = ce[bin];
          float a0[8], a1[8], b0[8], b1[8];
          #pragma unroll
          for (int j = 0; j < 8; j++){ a0[j]=0.f; a1[j]=0.f; b0[j]=0.f; b1[j]=0.f; }
          for (int i = s; i < e; i++){
            int srcn = sorted[i];
            const unsigned short* rh = H + (size_t)srcn*128 + r8*8;
            const unsigned short* rx = X + (size_t)srcn*128 + r8*8;
            short8 v0 = *(const short8*)rh;
            short8 v1 = *(const short8*)(rh + 64);
            short8 u0 = *(const short8*)rx;
            short8 u1 = *(const short8*)(rx + 64);
            #pragma unroll
            for (int j = 0; j < 8; j++){
              a0[j] += bf2f((unsigned short)v0[j]); a1[j] += bf2f((unsigned short)v1[j]);
              b0[j] += bf2f((unsigned short)u0[j]); b1[j] += bf2f((unsigned short)u1[j]);
            }
          }
          short8 o0,o1,p0,p1;
          #pragma unroll
          for (int j = 0; j < 8; j++){
            o0[j]=(short)f2bf(a0[j]); o1[j]=(short)f2bf(a1[j]);
            p0[j]=(short)f2bf(b0[j]); p1[j]=(short)f2bf(b1[j]);
          }
          *(short8*)&agg [nl*136 + r8*8]      = o0;
          *(short8*)&agg [nl*136 + 64 + r8*8] = o1;
          *(short8*)&agg2[nl*136 + r8*8]      = p0;
          *(short8*)&agg2[nl*136 + 64 + r8*8] = p1;
        }
        __syncthreads();
        mfma_tile(acc, agg, Wf, w, q, r);          // d==0 -> Wf + 0
        mfma_tile(sca, agg2, W3f, w, q, r);
        __syncthreads();
        continue;
      }
    }
    gather_dir(H, rs, ce, sorted, agg, m0, d, g, r8);
    __syncthreads();
    mfma_tile(acc, agg, Wf + (size_t)d*128*128, w, q, r);
    __syncthreads();
  }

  // epilogue: row = m0 + w*16 + q*4 + rr; col = ns*16 + r
  #pragma unroll
  for (int ns = 0; ns < 8; ns++){
    int col = ns*16 + r;
    float bA = biasA[col];
    if constexpr (!IS_L2){
      #pragma unroll
      for (int rr = 0; rr < 4; rr++){
        int row = m0 + w*16 + q*4 + rr;
        outB[(size_t)row*128 + col] = f2bf(elu1(acc[ns][rr] + bA));
      }
    } else {
      float b3 = bias3[col], s3 = s3v[col];
      #pragma unroll
      for (int rr = 0; rr < 4; rr++){
        int row = m0 + w*16 + q*4 + rr;
        float h = elu1(acc[ns][rr] + bA);
        outF[(size_t)row*128 + col] = elu1(h*s3 + sca[ns][rr] + b3);
      }
    }
  }
}

extern "C" void kernel_launch(void* const* d_in, const int* in_sizes, int n_in,
                              void* d_out, int out_size, void* d_ws, size_t ws_size,
                              hipStream_t stream){
  const float* x   = (const float*)d_in[0];
  const int*   ei  = (const int*)d_in[1];
  const int*   sel = (const int*)d_in[2];
  const float* W1  = (const float*)d_in[3];
  const float* b1  = (const float*)d_in[4];
  const float* g1  = (const float*)d_in[5];
  const float* be1 = (const float*)d_in[6];
  const float* rm1 = (const float*)d_in[7];
  const float* rv1 = (const float*)d_in[8];
  const float* W2  = (const float*)d_in[9];
  const float* b2  = (const float*)d_in[10];
  const float* g2  = (const float*)d_in[11];
  const float* be2 = (const float*)d_in[12];
  const float* rm2 = (const float*)d_in[13];
  const float* rv2 = (const float*)d_in[14];
  const float* W3  = (const float*)d_in[15];
  const float* b3  = (const float*)d_in[16];
  const float* g3  = (const float*)d_in[17];
  const float* be3 = (const float*)d_in[18];
  const float* rm3 = (const float*)d_in[19];
  const float* rv3 = (const float*)d_in[20];

  char* ws = (char*)d_ws;
  unsigned short* xb   = (unsigned short*)(ws);                  // 16.78 MB
  unsigned short* h1   = (unsigned short*)(ws + 16777216);       // 16.78 MB
  unsigned short* Wt1  = (unsigned short*)(ws + 33554432);       // 327,680 B (incl. W3fold @ rows 1152+)
  unsigned short* Wt2  = (unsigned short*)(ws + 33882112);       // 294,912 B
  float* bias1  = (float*)(ws + 34177024);
  float* bias2  = bias1 + 128;
  float* bias3  = bias1 + 256;
  float* s3v    = bias1 + 384;
  int* hist     = (int*)(ws + 34179072);                         // 4 MB (NBINS)
  int* rs       = (int*)(ws + 38373376);                         // 4 MB
  int* cursor   = (int*)(ws + 42567680);                         // 4 MB
  int* bsum     = (int*)(ws + 46761984);                         // 4 KB (1024)
  int* bsumx    = (int*)(ws + 46766080);                         // 4 KB
  int* bsumT    = (int*)(ws + 46770176);                         // 16 B
  int* sorted   = (int*)(ws + 46770432);                         // 2.36 MB; end ~49.1 MB

  const int* srcp = ei;
  const int* dstp = ei + NEDGE;

  hipMemsetAsync(hist, 0, NBINS*sizeof(int), stream);
  prep_w<<<1216, 256, 0, stream>>>(W1, W2, W3, g1, rv1, g2, rv2, g3, rv3, Wt1, Wt2);
  prep_bias<<<1, 128, 0, stream>>>(b1,g1,be1,rm1,rv1, b2,g2,be2,rm2,rv2, b3,g3,be3,rm3,rv3,
                                   bias1, bias2, bias3, s3v);
  xcast_k<<<4096, 256, 0, stream>>>(x, xb);
  hist_k<<<NEDGE/256, 256, 0, stream>>>(dstp, sel, hist);
  scan1_k<<<NBINS/1024, 256, 0, stream>>>(hist, rs, bsum);       // 1024 blocks
  scan1_k<<<1, 256, 0, stream>>>(bsum, bsumx, bsumT);            // scan the 1024 block sums
  scan3_k<<<NBINS/256, 256, 0, stream>>>(rs, bsumx, cursor);
  scatter_k<<<NEDGE/256, 256, 0, stream>>>(srcp, dstp, sel, cursor, sorted);

  layer_k<0><<<1024, 256, 0, stream>>>(xb, nullptr, Wt1, nullptr, rs, cursor, sorted,
                                       bias1, nullptr, nullptr, h1, nullptr);
  layer_k<1><<<1024, 256, 0, stream>>>(h1, xb, Wt2, Wt1 + 1152*128, rs, cursor, sorted,
                                       bias2, bias3, s3v, nullptr, (float*)d_out);
}

// Round 5
// 407.142 us; speedup vs baseline: 1.6370x; 1.6370x over previous
//
#include <hip/hip_runtime.h>
#include <hip/hip_bf16.h>
#include <math.h>

#define N_NODES 65536
#define NDIR 9
#define NEDGE 589824
#define NBINS (N_NODES*16)          // bin = dst*16 + sel

typedef __attribute__((ext_vector_type(8))) short short8;
typedef __attribute__((ext_vector_type(4))) float f32x4;

__device__ inline float bf2f(unsigned short u){ return __uint_as_float(((unsigned int)u)<<16); }
__device__ inline unsigned short f2bf(float f){
  unsigned int x = __float_as_uint(f);
  x += 0x7fff + ((x>>16)&1);           // round-to-nearest-even
  return (unsigned short)(x>>16);
}
__device__ inline float elu1(float x){ return x>0.f ? x : expm1f(x); }

// ---- prep: fold BN scale into W, transpose to [n][k] bf16 ----
// Wt1 rows 0..1151 = conv1 dirs, rows 1152..1279 = W3*s3 (shortcut). Wt2 = conv2 dirs.
__global__ void prep_w(const float* __restrict__ W1, const float* __restrict__ W2,
                       const float* __restrict__ W3,
                       const float* __restrict__ g1, const float* __restrict__ rv1,
                       const float* __restrict__ g2, const float* __restrict__ rv2,
                       const float* __restrict__ g3, const float* __restrict__ rv3,
                       unsigned short* __restrict__ Wt1, unsigned short* __restrict__ Wt2){
  int idx = blockIdx.x*256 + threadIdx.x;
  const float eps = 1e-5f;
  if (idx < 1280*128) {
    int n = idx >> 7, k = idx & 127;
    float v;
    if (n < 1152) { int d = n >> 7, c = n & 127;
      float s = g1[c]*rsqrtf(rv1[c]+eps); v = W1[(d*128 + k)*128 + c] * s; }
    else { int c = n - 1152;
      float s = g3[c]*rsqrtf(rv3[c]+eps); v = W3[k*128 + c] * s; }
    Wt1[idx] = f2bf(v);
  } else {
    int j = idx - 1280*128;
    int n = j >> 7, k = j & 127;
    int d = n >> 7, c = n & 127;
    float s = g2[c]*rsqrtf(rv2[c]+eps);
    Wt2[j] = f2bf(W2[(d*128 + k)*128 + c] * s);
  }
}

__global__ void prep_bias(const float* b1,const float* g1,const float* be1,const float* rm1,const float* rv1,
                          const float* b2,const float* g2,const float* be2,const float* rm2,const float* rv2,
                          const float* b3,const float* g3,const float* be3,const float* rm3,const float* rv3,
                          float* bias1, float* bias2, float* bias3, float* s3v){
  int c = threadIdx.x;
  const float eps = 1e-5f;
  float s1 = g1[c]*rsqrtf(rv1[c]+eps);
  bias1[c] = (b1[c]-rm1[c])*s1 + be1[c];
  float s2 = g2[c]*rsqrtf(rv2[c]+eps);
  bias2[c] = (b2[c]-rm2[c])*s2 + be2[c];
  float s3 = g3[c]*rsqrtf(rv3[c]+eps);
  bias3[c] = (b3[c]-rm3[c])*s3 + be3[c];   // s3 itself folded into Wt3
  s3v[c] = s3;
}

// ---- cast x to bf16 once ----
__global__ void xcast_k(const float* __restrict__ x, unsigned short* __restrict__ xb){
  int i = (blockIdx.x*256 + threadIdx.x)*8;
  f32x4 f0 = *(const f32x4*)(x + i);
  f32x4 f1 = *(const f32x4*)(x + i + 4);
  short8 t;
  #pragma unroll
  for (int j = 0; j < 4; j++){ t[j] = (short)f2bf(f0[j]); t[4+j] = (short)f2bf(f1[j]); }
  *(short8*)(xb + i) = t;
}

// ---- CSR build over (dst,sel) bins ----
__global__ void hist_k(const int* __restrict__ dst, const int* __restrict__ sel,
                       int* __restrict__ hist){
  int e = blockIdx.x*256 + threadIdx.x;
  atomicAdd(&hist[dst[e]*16 + sel[e]], 1);
}

// exclusive scan of 1024 ints per block; block total -> bsum[blockIdx]
__global__ void scan1_k(const int* __restrict__ in, int* __restrict__ out, int* __restrict__ bsum){
  __shared__ int wsum[4];
  int t = threadIdx.x;
  int base = blockIdx.x*1024 + t*4;
  int4 v = *(const int4*)(in + base);
  int s = v.x + v.y + v.z + v.w;
  int lane = t & 63, w = t >> 6;
  int inc = s;
  #pragma unroll
  for (int o = 1; o < 64; o <<= 1){ int n = __shfl_up(inc, o); if (lane >= o) inc += n; }
  if (lane == 63) wsum[w] = inc;
  __syncthreads();
  int acc = 0;
  for (int i = 0; i < w; i++) acc += wsum[i];
  int ex = acc + inc - s;
  out[base] = ex; out[base+1] = ex + v.x; out[base+2] = ex + v.x + v.y; out[base+3] = ex + v.x + v.y + v.z;
  if (t == 255) bsum[blockIdx.x] = acc + inc;
}

__global__ void scan3_k(int* __restrict__ rs, const int* __restrict__ bsumx, int* __restrict__ cursor){
  int i = blockIdx.x*256 + threadIdx.x;
  int v = rs[i] + bsumx[i >> 10];
  rs[i] = v; cursor[i] = v;
}

__global__ void scatter_k(const int* __restrict__ src, const int* __restrict__ dst,
                          const int* __restrict__ sel,
                          int* __restrict__ cursor, int* __restrict__ sorted){
  int e = blockIdx.x*256 + threadIdx.x;
  int bin = dst[e]*16 + sel[e];
  int pos = atomicAdd(&cursor[bin], 1);
  sorted[pos] = src[e];                 // after scatter, cursor[bin] == end
}

// ---- gather one direction's aggregate tile for 64 dst nodes into LDS ----
// 16 lanes per row (lane role: g16 = which of 4 rows in flight, c = 16B chunk).
// Registers: 2x f32x4 accum + 1 short8 -> no spill.
__device__ inline void gather_phase(const unsigned short* __restrict__ act,
                                    const int* __restrict__ rs, const int* __restrict__ ce,
                                    const int* __restrict__ sorted,
                                    unsigned short* __restrict__ agg,
                                    int m0, int d, int w, int g16, int c){
  #pragma unroll
  for (int t = 0; t < 4; t++){
    int nl = w*16 + t*4 + g16;
    int bin = (m0 + nl)*16 + d;
    int s = rs[bin], e = ce[bin];
    f32x4 a0 = {0.f,0.f,0.f,0.f}, a1 = {0.f,0.f,0.f,0.f};
    for (int i = s; i < e; i++){
      int srcn = sorted[i];
      short8 v = *(const short8*)(act + (size_t)srcn*128 + c*8);
      a0[0] += bf2f((unsigned short)v[0]); a0[1] += bf2f((unsigned short)v[1]);
      a0[2] += bf2f((unsigned short)v[2]); a0[3] += bf2f((unsigned short)v[3]);
      a1[0] += bf2f((unsigned short)v[4]); a1[1] += bf2f((unsigned short)v[5]);
      a1[2] += bf2f((unsigned short)v[6]); a1[3] += bf2f((unsigned short)v[7]);
    }
    short8 o;
    o[0]=(short)f2bf(a0[0]); o[1]=(short)f2bf(a0[1]); o[2]=(short)f2bf(a0[2]); o[3]=(short)f2bf(a0[3]);
    o[4]=(short)f2bf(a1[0]); o[5]=(short)f2bf(a1[1]); o[6]=(short)f2bf(a1[2]); o[7]=(short)f2bf(a1[3]);
    *(short8*)&agg[nl*136 + c*8] = o;
  }
}

// ---- MFMA: wave computes 64 rows x 32 cols (cols [w*32, w*32+32)) ----
// B-traffic: 2 frags/kk/wave -> whole block reads W_d exactly once per phase.
__device__ inline void mfma_tile(f32x4 acc[4][2], const unsigned short* agg,
                                 const unsigned short* __restrict__ Wd,
                                 int w, int q, int r){
  #pragma unroll
  for (int kk = 0; kk < 4; kk++){
    short8 bv[2];
    #pragma unroll
    for (int n2 = 0; n2 < 2; n2++)
      bv[n2] = *(const short8*)(Wd + (size_t)(w*32 + n2*16 + r)*128 + kk*32 + q*8);
    #pragma unroll
    for (int mt = 0; mt < 4; mt++){
      short8 av = *(const short8*)&agg[(mt*16 + r)*136 + kk*32 + q*8];
      #pragma unroll
      for (int n2 = 0; n2 < 2; n2++)
        acc[mt][n2] = __builtin_amdgcn_mfma_f32_16x16x32_bf16(av, bv[n2], acc[mt][n2], 0, 0, 0);
    }
  }
}

template<int IS_L2>
__global__ __launch_bounds__(256, 4 - IS_L2) void layer_k(
    const unsigned short* __restrict__ H,     // layer input activations [N][128] bf16
    const unsigned short* __restrict__ X,     // xb (shortcut input, L2 only)
    const unsigned short* __restrict__ Wf,    // [1152][128] folded dir weights
    const unsigned short* __restrict__ W3f,   // [128][128] folded shortcut weights (L2)
    const int* __restrict__ rs, const int* __restrict__ ce, const int* __restrict__ sorted,
    const float* __restrict__ biasA, const float* __restrict__ bias3,
    const float* __restrict__ s3v,
    unsigned short* __restrict__ outB, float* __restrict__ outF){
  __shared__ __align__(16) unsigned short agg[64*136];   // 17.4 KB single tile
  const int tid = threadIdx.x;
  const int w = tid >> 6, lane = tid & 63;
  const int q = lane >> 4, r = lane & 15;
  const int m0 = blockIdx.x * 64;

  f32x4 acc[4][2];
  #pragma unroll
  for (int mt = 0; mt < 4; mt++){ acc[mt][0] = (f32x4){0,0,0,0}; acc[mt][1] = (f32x4){0,0,0,0}; }

  #pragma unroll 1
  for (int d = 0; d < 9; d++){
    gather_phase(H, rs, ce, sorted, agg, m0, d, w, q, r);
    __syncthreads();
    mfma_tile(acc, agg, Wf + (size_t)d*128*128, w, q, r);
    __syncthreads();
  }

  if constexpr (!IS_L2){
    #pragma unroll
    for (int mt = 0; mt < 4; mt++)
      #pragma unroll
      for (int n2 = 0; n2 < 2; n2++){
        int col = w*32 + n2*16 + r;
        float bA = biasA[col];
        #pragma unroll
        for (int rr = 0; rr < 4; rr++){
          int row = m0 + mt*16 + q*4 + rr;
          outB[(size_t)row*128 + col] = f2bf(elu1(acc[mt][n2][rr] + bA));
        }
      }
  } else {
    // 10th phase: shortcut gather over sel==0 edges from X, MFMA with W3f
    f32x4 sca[4][2];
    #pragma unroll
    for (int mt = 0; mt < 4; mt++){ sca[mt][0] = (f32x4){0,0,0,0}; sca[mt][1] = (f32x4){0,0,0,0}; }
    gather_phase(X, rs, ce, sorted, agg, m0, 0, w, q, r);
    __syncthreads();
    mfma_tile(sca, agg, W3f, w, q, r);
    #pragma unroll
    for (int mt = 0; mt < 4; mt++)
      #pragma unroll
      for (int n2 = 0; n2 < 2; n2++){
        int col = w*32 + n2*16 + r;
        float bA = biasA[col], b3 = bias3[col], s3 = s3v[col];
        #pragma unroll
        for (int rr = 0; rr < 4; rr++){
          int row = m0 + mt*16 + q*4 + rr;
          float h = elu1(acc[mt][n2][rr] + bA);
          outF[(size_t)row*128 + col] = elu1(h*s3 + sca[mt][n2][rr] + b3);
        }
      }
  }
}

extern "C" void kernel_launch(void* const* d_in, const int* in_sizes, int n_in,
                              void* d_out, int out_size, void* d_ws, size_t ws_size,
                              hipStream_t stream){
  const float* x   = (const float*)d_in[0];
  const int*   ei  = (const int*)d_in[1];
  const int*   sel = (const int*)d_in[2];
  const float* W1  = (const float*)d_in[3];
  const float* b1  = (const float*)d_in[4];
  const float* g1  = (const float*)d_in[5];
  const float* be1 = (const float*)d_in[6];
  const float* rm1 = (const float*)d_in[7];
  const float* rv1 = (const float*)d_in[8];
  const float* W2  = (const float*)d_in[9];
  const float* b2  = (const float*)d_in[10];
  const float* g2  = (const float*)d_in[11];
  const float* be2 = (const float*)d_in[12];
  const float* rm2 = (const float*)d_in[13];
  const float* rv2 = (const float*)d_in[14];
  const float* W3  = (const float*)d_in[15];
  const float* b3  = (const float*)d_in[16];
  const float* g3  = (const float*)d_in[17];
  const float* be3 = (const float*)d_in[18];
  const float* rm3 = (const float*)d_in[19];
  const float* rv3 = (const float*)d_in[20];

  char* ws = (char*)d_ws;
  unsigned short* xb   = (unsigned short*)(ws);                  // 16.78 MB
  unsigned short* h1   = (unsigned short*)(ws + 16777216);       // 16.78 MB
  unsigned short* Wt1  = (unsigned short*)(ws + 33554432);       // 327,680 B (incl. W3fold @ rows 1152+)
  unsigned short* Wt2  = (unsigned short*)(ws + 33882112);       // 294,912 B
  float* bias1  = (float*)(ws + 34177024);
  float* bias2  = bias1 + 128;
  float* bias3  = bias1 + 256;
  float* s3v    = bias1 + 384;
  int* hist     = (int*)(ws + 34179072);                         // 4 MB (NBINS)
  int* rs       = (int*)(ws + 38373376);                         // 4 MB
  int* cursor   = (int*)(ws + 42567680);                         // 4 MB
  int* bsum     = (int*)(ws + 46761984);                         // 4 KB (1024)
  int* bsumx    = (int*)(ws + 46766080);                         // 4 KB
  int* bsumT    = (int*)(ws + 46770176);                         // 16 B
  int* sorted   = (int*)(ws + 46770432);                         // 2.36 MB; end ~49.1 MB

  const int* srcp = ei;
  const int* dstp = ei + NEDGE;

  hipMemsetAsync(hist, 0, NBINS*sizeof(int), stream);
  prep_w<<<1216, 256, 0, stream>>>(W1, W2, W3, g1, rv1, g2, rv2, g3, rv3, Wt1, Wt2);
  prep_bias<<<1, 128, 0, stream>>>(b1,g1,be1,rm1,rv1, b2,g2,be2,rm2,rv2, b3,g3,be3,rm3,rv3,
                                   bias1, bias2, bias3, s3v);
  xcast_k<<<4096, 256, 0, stream>>>(x, xb);
  hist_k<<<NEDGE/256, 256, 0, stream>>>(dstp, sel, hist);
  scan1_k<<<NBINS/1024, 256, 0, stream>>>(hist, rs, bsum);       // 1024 blocks
  scan1_k<<<1, 256, 0, stream>>>(bsum, bsumx, bsumT);            // scan the 1024 block sums
  scan3_k<<<NBINS/256, 256, 0, stream>>>(rs, bsumx, cursor);
  scatter_k<<<NEDGE/256, 256, 0, stream>>>(srcp, dstp, sel, cursor, sorted);

  layer_k<0><<<1024, 256, 0, stream>>>(xb, nullptr, Wt1, nullptr, rs, cursor, sorted,
                                       bias1, nullptr, nullptr, h1, nullptr);
  layer_k<1><<<1024, 256, 0, stream>>>(h1, xb, Wt2, Wt1 + 1152*128, rs, cursor, sorted,
                                       bias2, bias3, s3v, nullptr, (float*)d_out);
}

// Round 6
// 372.672 us; speedup vs baseline: 1.7884x; 1.0925x over previous
//
#include <hip/hip_runtime.h>
#include <hip/hip_bf16.h>
#include <math.h>

#define N_NODES 65536
#define NDIR 9
#define NEDGE 589824
#define NBINS (N_NODES*NDIR)        // bin = dst*9 + sel (contiguous per node)
#define TILE_M 32
#define SKEY_CAP 1024

typedef __attribute__((ext_vector_type(8))) short short8;
typedef __attribute__((ext_vector_type(4))) float f32x4;

__device__ inline float bf2f(unsigned short u){ return __uint_as_float(((unsigned int)u)<<16); }
__device__ inline unsigned short f2bf(float f){
  unsigned int x = __float_as_uint(f);
  x += 0x7fff + ((x>>16)&1);           // round-to-nearest-even
  return (unsigned short)(x>>16);
}
__device__ inline float elu1(float x){ return x>0.f ? x : expm1f(x); }

// ---- prep: fold BN scale into W, transpose to [n][k] bf16 ----
// Wt1 rows 0..1151 = conv1 dirs, rows 1152..1279 = W3*s3 (shortcut). Wt2 = conv2 dirs.
__global__ void prep_w(const float* __restrict__ W1, const float* __restrict__ W2,
                       const float* __restrict__ W3,
                       const float* __restrict__ g1, const float* __restrict__ rv1,
                       const float* __restrict__ g2, const float* __restrict__ rv2,
                       const float* __restrict__ g3, const float* __restrict__ rv3,
                       unsigned short* __restrict__ Wt1, unsigned short* __restrict__ Wt2){
  int idx = blockIdx.x*256 + threadIdx.x;
  const float eps = 1e-5f;
  if (idx < 1280*128) {
    int n = idx >> 7, k = idx & 127;
    float v;
    if (n < 1152) { int d = n >> 7, c = n & 127;
      float s = g1[c]*rsqrtf(rv1[c]+eps); v = W1[(d*128 + k)*128 + c] * s; }
    else { int c = n - 1152;
      float s = g3[c]*rsqrtf(rv3[c]+eps); v = W3[k*128 + c] * s; }
    Wt1[idx] = f2bf(v);
  } else {
    int j = idx - 1280*128;
    int n = j >> 7, k = j & 127;
    int d = n >> 7, c = n & 127;
    float s = g2[c]*rsqrtf(rv2[c]+eps);
    Wt2[j] = f2bf(W2[(d*128 + k)*128 + c] * s);
  }
}

__global__ void prep_bias(const float* b1,const float* g1,const float* be1,const float* rm1,const float* rv1,
                          const float* b2,const float* g2,const float* be2,const float* rm2,const float* rv2,
                          const float* b3,const float* g3,const float* be3,const float* rm3,const float* rv3,
                          float* bias1, float* bias2, float* bias3, float* s3v){
  int c = threadIdx.x;
  const float eps = 1e-5f;
  float s1 = g1[c]*rsqrtf(rv1[c]+eps);
  bias1[c] = (b1[c]-rm1[c])*s1 + be1[c];
  float s2 = g2[c]*rsqrtf(rv2[c]+eps);
  bias2[c] = (b2[c]-rm2[c])*s2 + be2[c];
  float s3 = g3[c]*rsqrtf(rv3[c]+eps);
  bias3[c] = (b3[c]-rm3[c])*s3 + be3[c];   // s3 itself folded into Wt3
  s3v[c] = s3;
}

// ---- cast x to bf16 once ----
__global__ void xcast_k(const float* __restrict__ x, unsigned short* __restrict__ xb){
  int i = (blockIdx.x*256 + threadIdx.x)*8;
  f32x4 f0 = *(const f32x4*)(x + i);
  f32x4 f1 = *(const f32x4*)(x + i + 4);
  short8 t;
  #pragma unroll
  for (int j = 0; j < 4; j++){ t[j] = (short)f2bf(f0[j]); t[4+j] = (short)f2bf(f1[j]); }
  *(short8*)(xb + i) = t;
}

// ---- CSR build over (dst,sel) bins, bin = dst*9+sel ----
__global__ void hist_k(const int* __restrict__ dst, const int* __restrict__ sel,
                       int* __restrict__ hist){
  int e = blockIdx.x*256 + threadIdx.x;
  atomicAdd(&hist[dst[e]*9 + sel[e]], 1);
}

// exclusive scan of 1024 ints per block; block total -> bsum[blockIdx]
__global__ void scan1_k(const int* __restrict__ in, int* __restrict__ out, int* __restrict__ bsum){
  __shared__ int wsum[4];
  int t = threadIdx.x;
  int base = blockIdx.x*1024 + t*4;
  int4 v = *(const int4*)(in + base);
  int s = v.x + v.y + v.z + v.w;
  int lane = t & 63, w = t >> 6;
  int inc = s;
  #pragma unroll
  for (int o = 1; o < 64; o <<= 1){ int n = __shfl_up(inc, o); if (lane >= o) inc += n; }
  if (lane == 63) wsum[w] = inc;
  __syncthreads();
  int acc = 0;
  for (int i = 0; i < w; i++) acc += wsum[i];
  int ex = acc + inc - s;
  out[base] = ex; out[base+1] = ex + v.x; out[base+2] = ex + v.x + v.y; out[base+3] = ex + v.x + v.y + v.z;
  if (t == 255) bsum[blockIdx.x] = acc + inc;
}

__global__ void scan3_k(int* __restrict__ rs, const int* __restrict__ bsumx, int* __restrict__ cursor){
  int i = blockIdx.x*256 + threadIdx.x;
  int v = rs[i] + bsumx[i >> 10];
  rs[i] = v; cursor[i] = v;
  if (i == 0) rs[NBINS] = NEDGE;        // sentinel: end(bin b) == rs[b+1]
}

__global__ void scatter_k(const int* __restrict__ src, const int* __restrict__ dst,
                          const int* __restrict__ sel,
                          int* __restrict__ cursor, int* __restrict__ sorted){
  int e = blockIdx.x*256 + threadIdx.x;
  int bin = dst[e]*9 + sel[e];
  int pos = atomicAdd(&cursor[bin], 1);
  sorted[pos] = src[e];
}

// ---- MFMA: wave computes all 32 rows x 32 cols (cols [w*32,w*32+32)) ----
__device__ __forceinline__ void mfma_tile(f32x4 acc[2][2],
                                          const unsigned short* agg,
                                          const unsigned short* __restrict__ Wd,
                                          int w, int q, int r){
  #pragma unroll
  for (int kk = 0; kk < 4; kk++){
    const unsigned short* wp = Wd + (size_t)(w*32 + r)*128 + kk*32 + q*8;
    short8 b0 = *(const short8*)wp;
    short8 b1 = *(const short8*)(wp + 16*128);
    #pragma unroll
    for (int mt = 0; mt < 2; mt++){
      short8 av = *(const short8*)&agg[(mt*16 + r)*136 + kk*32 + q*8];
      acc[mt][0] = __builtin_amdgcn_mfma_f32_16x16x32_bf16(av, b0, acc[mt][0], 0, 0, 0);
      acc[mt][1] = __builtin_amdgcn_mfma_f32_16x16x32_bf16(av, b1, acc[mt][1], 0, 0, 0);
    }
  }
}

// ---- fused layer: per 32-node block, per dir: gather-sum rows -> LDS, MFMA @ W_d.
// Block-local CSR (bin offsets + edge keys) preloaded into LDS once.
template<int IS_L2>
__global__ __launch_bounds__(256, 8) void layer_k(
    const unsigned short* __restrict__ H,     // layer input activations [N][128] bf16
    const unsigned short* __restrict__ X,     // xb (shortcut input, L2 only)
    const unsigned short* __restrict__ Wf,    // [1152][128] folded dir weights
    const unsigned short* __restrict__ W3f,   // [128][128] folded shortcut weights (L2)
    const int* __restrict__ rs, const int* __restrict__ sorted,
    const float* __restrict__ biasA, const float* __restrict__ bias3,
    const float* __restrict__ s3v,
    unsigned short* __restrict__ outB, float* __restrict__ outF){
  __shared__ __align__(16) unsigned short agg[TILE_M*136];   // 8.7 KB
  __shared__ int skey[SKEY_CAP];                              // 4 KB block edge keys
  __shared__ int rsl[TILE_M*9 + 1];                           // block bin offsets
  const int tid = threadIdx.x;
  const int w = tid >> 6, lane = tid & 63;
  const int q = lane >> 4, r = lane & 15;
  const int rid = tid >> 4, c = tid & 15;                     // 16 lanes per row, 16B chunk c
  const int m0 = blockIdx.x * TILE_M;

  for (int i = tid; i <= TILE_M*9; i += 256) rsl[i] = rs[m0*9 + i];
  __syncthreads();
  const int lo = rsl[0];
  const int cnt = rsl[TILE_M*9] - lo;
  for (int i = tid; i < cnt && i < SKEY_CAP; i += 256) skey[i] = sorted[lo + i];

  f32x4 acc[2][2];
  #pragma unroll
  for (int mt = 0; mt < 2; mt++){ acc[mt][0] = (f32x4){0,0,0,0}; acc[mt][1] = (f32x4){0,0,0,0}; }

  #pragma unroll 1
  for (int d = 0; d < 9; d++){
    __syncthreads();                     // skey ready (d=0) / agg consumed (d>0)
    #pragma unroll
    for (int t = 0; t < 2; t++){
      int nl = t*16 + rid;
      int b = nl*9 + d;
      int s = rsl[b] - lo, e = rsl[b+1] - lo;
      f32x4 a0 = {0,0,0,0}, a1 = {0,0,0,0};
      for (int i = s; i < e; i++){
        int key = (i < SKEY_CAP) ? skey[i] : sorted[lo + i];
        short8 v = *(const short8*)(H + (size_t)key*128 + c*8);
        a0[0] += bf2f((unsigned short)v[0]); a0[1] += bf2f((unsigned short)v[1]);
        a0[2] += bf2f((unsigned short)v[2]); a0[3] += bf2f((unsigned short)v[3]);
        a1[0] += bf2f((unsigned short)v[4]); a1[1] += bf2f((unsigned short)v[5]);
        a1[2] += bf2f((unsigned short)v[6]); a1[3] += bf2f((unsigned short)v[7]);
      }
      short8 o;
      o[0]=(short)f2bf(a0[0]); o[1]=(short)f2bf(a0[1]); o[2]=(short)f2bf(a0[2]); o[3]=(short)f2bf(a0[3]);
      o[4]=(short)f2bf(a1[0]); o[5]=(short)f2bf(a1[1]); o[6]=(short)f2bf(a1[2]); o[7]=(short)f2bf(a1[3]);
      *(short8*)&agg[nl*136 + c*8] = o;
    }
    __syncthreads();
    mfma_tile(acc, agg, Wf + (size_t)d*128*128, w, q, r);
  }

  if constexpr (!IS_L2){
    #pragma unroll
    for (int mt = 0; mt < 2; mt++)
      #pragma unroll
      for (int n2 = 0; n2 < 2; n2++){
        int col = w*32 + n2*16 + r;
        float bA = biasA[col];
        #pragma unroll
        for (int rr = 0; rr < 4; rr++){
          int row = m0 + mt*16 + q*4 + rr;
          outB[(size_t)row*128 + col] = f2bf(elu1(acc[mt][n2][rr] + bA));
        }
      }
  } else {
    // 10th phase: shortcut gather over sel==0 edges from X, MFMA with W3f
    f32x4 sca[2][2];
    #pragma unroll
    for (int mt = 0; mt < 2; mt++){ sca[mt][0] = (f32x4){0,0,0,0}; sca[mt][1] = (f32x4){0,0,0,0}; }
    __syncthreads();                     // agg consumed by last mfma
    #pragma unroll
    for (int t = 0; t < 2; t++){
      int nl = t*16 + rid;
      int b = nl*9;
      int s = rsl[b] - lo, e = rsl[b+1] - lo;
      f32x4 a0 = {0,0,0,0}, a1 = {0,0,0,0};
      for (int i = s; i < e; i++){
        int key = (i < SKEY_CAP) ? skey[i] : sorted[lo + i];
        short8 v = *(const short8*)(X + (size_t)key*128 + c*8);
        a0[0] += bf2f((unsigned short)v[0]); a0[1] += bf2f((unsigned short)v[1]);
        a0[2] += bf2f((unsigned short)v[2]); a0[3] += bf2f((unsigned short)v[3]);
        a1[0] += bf2f((unsigned short)v[4]); a1[1] += bf2f((unsigned short)v[5]);
        a1[2] += bf2f((unsigned short)v[6]); a1[3] += bf2f((unsigned short)v[7]);
      }
      short8 o;
      o[0]=(short)f2bf(a0[0]); o[1]=(short)f2bf(a0[1]); o[2]=(short)f2bf(a0[2]); o[3]=(short)f2bf(a0[3]);
      o[4]=(short)f2bf(a1[0]); o[5]=(short)f2bf(a1[1]); o[6]=(short)f2bf(a1[2]); o[7]=(short)f2bf(a1[3]);
      *(short8*)&agg[nl*136 + c*8] = o;
    }
    __syncthreads();
    mfma_tile(sca, agg, W3f, w, q, r);
    #pragma unroll
    for (int mt = 0; mt < 2; mt++)
      #pragma unroll
      for (int n2 = 0; n2 < 2; n2++){
        int col = w*32 + n2*16 + r;
        float bA = biasA[col], b3 = bias3[col], s3 = s3v[col];
        #pragma unroll
        for (int rr = 0; rr < 4; rr++){
          int row = m0 + mt*16 + q*4 + rr;
          float h = elu1(acc[mt][n2][rr] + bA);
          outF[(size_t)row*128 + col] = elu1(h*s3 + sca[mt][n2][rr] + b3);
        }
      }
  }
}

extern "C" void kernel_launch(void* const* d_in, const int* in_sizes, int n_in,
                              void* d_out, int out_size, void* d_ws, size_t ws_size,
                              hipStream_t stream){
  const float* x   = (const float*)d_in[0];
  const int*   ei  = (const int*)d_in[1];
  const int*   sel = (const int*)d_in[2];
  const float* W1  = (const float*)d_in[3];
  const float* b1  = (const float*)d_in[4];
  const float* g1  = (const float*)d_in[5];
  const float* be1 = (const float*)d_in[6];
  const float* rm1 = (const float*)d_in[7];
  const float* rv1 = (const float*)d_in[8];
  const float* W2  = (const float*)d_in[9];
  const float* b2  = (const float*)d_in[10];
  const float* g2  = (const float*)d_in[11];
  const float* be2 = (const float*)d_in[12];
  const float* rm2 = (const float*)d_in[13];
  const float* rv2 = (const float*)d_in[14];
  const float* W3  = (const float*)d_in[15];
  const float* b3  = (const float*)d_in[16];
  const float* g3  = (const float*)d_in[17];
  const float* be3 = (const float*)d_in[18];
  const float* rm3 = (const float*)d_in[19];
  const float* rv3 = (const float*)d_in[20];

  char* ws = (char*)d_ws;
  unsigned short* xb   = (unsigned short*)(ws);                  // 16.78 MB
  unsigned short* h1   = (unsigned short*)(ws + 16777216);       // 16.78 MB
  unsigned short* Wt1  = (unsigned short*)(ws + 33554432);       // 327,680 B (incl. W3fold @ rows 1152+)
  unsigned short* Wt2  = (unsigned short*)(ws + 33882112);       // 294,912 B
  float* bias1  = (float*)(ws + 34177024);
  float* bias2  = bias1 + 128;
  float* bias3  = bias1 + 256;
  float* s3v    = bias1 + 384;
  int* hist     = (int*)(ws + 34179072);                         // NBINS*4 = 2.36 MB
  int* rs       = (int*)(ws + 36538368);                         // (NBINS+1)*4
  int* cursor   = (int*)(ws + 38897920);                         // NBINS*4
  int* bsum     = (int*)(ws + 41257216);                         // 4 KB
  int* bsumx    = (int*)(ws + 41261312);                         // 4 KB
  int* bsumT    = (int*)(ws + 41265408);                         // 16 B
  int* sorted   = (int*)(ws + 41265664);                         // NBINS*4; end ~43.6 MB

  const int* srcp = ei;
  const int* dstp = ei + NEDGE;

  hipMemsetAsync(hist, 0, NBINS*sizeof(int), stream);
  prep_w<<<1216, 256, 0, stream>>>(W1, W2, W3, g1, rv1, g2, rv2, g3, rv3, Wt1, Wt2);
  prep_bias<<<1, 128, 0, stream>>>(b1,g1,be1,rm1,rv1, b2,g2,be2,rm2,rv2, b3,g3,be3,rm3,rv3,
                                   bias1, bias2, bias3, s3v);
  xcast_k<<<4096, 256, 0, stream>>>(x, xb);
  hist_k<<<NEDGE/256, 256, 0, stream>>>(dstp, sel, hist);
  scan1_k<<<NBINS/1024, 256, 0, stream>>>(hist, rs, bsum);       // 576 blocks
  scan1_k<<<1, 256, 0, stream>>>(bsum, bsumx, bsumT);            // scan 576 block sums (tail garbage harmless)
  scan3_k<<<NBINS/256, 256, 0, stream>>>(rs, bsumx, cursor);
  scatter_k<<<NEDGE/256, 256, 0, stream>>>(srcp, dstp, sel, cursor, sorted);

  layer_k<0><<<2048, 256, 0, stream>>>(xb, nullptr, Wt1, nullptr, rs, sorted,
                                       bias1, nullptr, nullptr, h1, nullptr);
  layer_k<1><<<2048, 256, 0, stream>>>(h1, xb, Wt2, Wt1 + 1152*128, rs, sorted,
                                       bias2, bias3, s3v, nullptr, (float*)d_out);
}